// Round 3
// baseline (512.239 us; speedup 1.0000x reference)
//
#include <hip/hip_runtime.h>

#define NN 10000
#define EE 320000
#define HH 256

__device__ float bf2f(unsigned int v) {
    return __uint_as_float(v << 16);
}
__device__ unsigned short f2bf(float f) {
    unsigned int i = __float_as_uint(f);
    return (unsigned short)((i + 0x7fffu + ((i >> 16) & 1u)) >> 16);
}

// ---- 0. Detect input dtypes from raw bits. flags[0]: edge_index is int64.
//         flags[1]: float inputs are f32 (else bf16).
__global__ void k_detect(const unsigned int* xu, const unsigned int* eu, int* flags) {
    if (threadIdx.x != 0 || blockIdx.x != 0) return;
    int odd_nonzero = 0;
    for (int k = 0; k < 256; k++) {
        if (eu[2 * k + 1] != 0) odd_nonzero = 1;
    }
    flags[0] = odd_nonzero ? 0 : 1;
    int plausible = 0;
    for (int k = 0; k < 64; k++) {
        unsigned int lo = xu[k] & 0xffffu;
        unsigned int ex = (lo >> 7) & 0xffu;
        if (lo == 0u || (ex >= 90u && ex <= 150u)) plausible++;
    }
    flags[1] = (plausible >= 56) ? 0 : 1;
}

__device__ int eload(const void* ei, int is64, int idx) {
    if (is64) return (int)(((const long long*)ei)[idx]);
    return ((const int*)ei)[idx];
}

// ---- 1. zero the atomically-built arrays (ws is poisoned 0xAA each call)
__global__ void k_zero3(int* a, int* b, int* c) {
    int i = blockIdx.x * 256 + threadIdx.x;
    if (i < NN) { a[i] = 0; b[i] = 0; c[i] = 0; }
}

// ---- 2. raw per-row edge counts (duplicates included)
__global__ void k_count(const void* ei, const int* flags, int* rawcnt) {
    int e = blockIdx.x * 256 + threadIdx.x;
    if (e >= EE) return;
    int is64 = flags[0];
    int r = eload(ei, is64, e);
    int c = eload(ei, is64, EE + e);
    if (r < 0 || r >= NN || c < 0 || c >= NN) return;
    atomicAdd(&rawcnt[r], 1);
}

// ---- 3. exclusive prefix sum over rawcnt -> row_start[0..NN], single block
__global__ void k_scan(const int* cnt, int* row_start) {
    __shared__ int part[256];
    int t = threadIdx.x;
    int base = t * 40;                      // 256*40 = 10240 >= NN+1
    int s = 0;
    for (int k = 0; k < 40; k++) { int i = base + k; if (i < NN) s += cnt[i]; }
    part[t] = s;
    __syncthreads();
    for (int off = 1; off < 256; off <<= 1) {
        int add = (t >= off) ? part[t - off] : 0;
        __syncthreads();
        part[t] += add;
        __syncthreads();
    }
    int run = part[t] - s;
    for (int k = 0; k < 40; k++) {
        int i = base + k;
        if (i <= NN) row_start[i] = run;
        if (i < NN) run += cnt[i];
    }
}

// ---- 4. scatter columns into raw CSR slots
__global__ void k_fill(const void* ei, const int* flags, const int* row_start,
                       int* fillc, int* col) {
    int e = blockIdx.x * 256 + threadIdx.x;
    if (e >= EE) return;
    int is64 = flags[0];
    int r = eload(ei, is64, e);
    int c = eload(ei, is64, EE + e);
    if (r < 0 || r >= NN || c < 0 || c >= NN) return;
    int pos = row_start[r] + atomicAdd(&fillc[r], 1);
    col[pos] = c;
}

// ---- 5. per-row dedupe (one wave per row): compact unique cols, count degrees
__global__ void k_dedup(const int* row_start, int* col, int* deg_r, int* deg_c) {
    __shared__ int lds[192];
    __shared__ int cnt;
    int i = blockIdx.x;
    int lane = threadIdx.x;
    int s = row_start[i];
    int d = row_start[i + 1] - s;
    if (d > 192) d = 192;                  // raw deg ~ Poisson(32); never hit
    if (lane == 0) cnt = 0;
    for (int t = lane; t < d; t += 64) lds[t] = col[s + t];
    __syncthreads();
    for (int t = lane; t < d; t += 64) {
        int c = lds[t];
        int dup = 0;
        for (int u = 0; u < t; u++) { if (lds[u] == c) dup = 1; }
        if (!dup) {
            int p = atomicAdd(&cnt, 1);
            col[s + p] = c;                // compacted unique prefix of the row
            atomicAdd(&deg_c[c], 1);
        }
    }
    __syncthreads();
    if (lane == 0) deg_r[i] = cnt;
}

// ---- 6. dinv = deg>0 ? rsqrt(deg) : 0
__global__ void k_dinv(const int* deg_r, const int* deg_c, float* dinv_r, float* dinv_c) {
    int i = blockIdx.x * 256 + threadIdx.x;
    if (i >= NN) return;
    int dr = deg_r[i], dc = deg_c[i];
    dinv_r[i] = dr > 0 ? rsqrtf((float)dr) : 0.0f;
    dinv_c[i] = dc > 0 ? rsqrtf((float)dc) : 0.0f;
}

// ---- 7. VALU GEMM: C[M x 256](f32) = A[M x 256] @ B[256 x 256].
//  amode=1: A is f32 workspace. amode=0: A is the input x (dtype per flags[1]).
//  B (weights) dtype per flags[1]. 8 rows per block; thread t owns column t.
__global__ void k_gemm8(const void* A, int amode, const void* B, float* C, int M,
                        const int* flags) {
    __shared__ float As[8][256];
    int t = threadIdx.x;
    int r0 = blockIdx.x * 8;
    int f32in = flags[1];
    int af32 = amode ? 1 : f32in;
    for (int j = 0; j < 8; j++) {
        int r = r0 + j;
        float v = 0.0f;
        if (r < M) {
            if (af32) v = ((const float*)A)[(size_t)r * HH + t];
            else      v = bf2f((unsigned int)((const unsigned short*)A)[(size_t)r * HH + t]);
        }
        As[j][t] = v;
    }
    __syncthreads();
    float a0 = 0.f, a1 = 0.f, a2 = 0.f, a3 = 0.f, a4 = 0.f, a5 = 0.f, a6 = 0.f, a7 = 0.f;
    if (f32in) {
        const float* Bf = (const float*)B;
        for (int k = 0; k < 256; k++) {
            float bv = Bf[(size_t)k * HH + t];
            a0 += As[0][k] * bv; a1 += As[1][k] * bv;
            a2 += As[2][k] * bv; a3 += As[3][k] * bv;
            a4 += As[4][k] * bv; a5 += As[5][k] * bv;
            a6 += As[6][k] * bv; a7 += As[7][k] * bv;
        }
    } else {
        const unsigned short* Bh = (const unsigned short*)B;
        for (int k = 0; k < 256; k++) {
            float bv = bf2f((unsigned int)Bh[(size_t)k * HH + t]);
            a0 += As[0][k] * bv; a1 += As[1][k] * bv;
            a2 += As[2][k] * bv; a3 += As[3][k] * bv;
            a4 += As[4][k] * bv; a5 += As[5][k] * bv;
            a6 += As[6][k] * bv; a7 += As[7][k] * bv;
        }
    }
    float acc[8];
    acc[0] = a0; acc[1] = a1; acc[2] = a2; acc[3] = a3;
    acc[4] = a4; acc[5] = a5; acc[6] = a6; acc[7] = a7;
    for (int j = 0; j < 8; j++) {
        int r = r0 + j;
        if (r < M) C[(size_t)r * HH + t] = acc[j];
    }
}

// ---- 8. SpMM row pass over compacted CSR. Y is f32.
//  high=1: O = Y[i] - dinv[i]*Sum_{j in row}(dinv[j]*Y[j]) + bias  (lsym)
//  high=0: O = dinv[i]*Sum + bias                                   (anorm)
//  relu: max(0,.).  Of != 0: write f32 to Of. else write to Oout (dtype per
//  flags[1]) at chunk c0 (and chunk c1 if c1 >= 0).
__global__ void k_spmm(const float* Y, const int* row_start, const int* col,
                       const int* ucnt, const float* dinv, const void* bias,
                       const int* flags, int high, int relu,
                       float* Of, void* Oout, int c0, int c1) {
    int wave = threadIdx.x >> 6;
    int lane = threadIdx.x & 63;
    int i = blockIdx.x * 4 + wave;          // grid = NN/4 exactly
    int f0 = lane * 4;
    float s0 = 0.f, s1 = 0.f, s2 = 0.f, s3 = 0.f;
    int s = row_start[i];
    int e = s + ucnt[i];
    for (int t = s; t < e; t++) {
        int c = col[t];
        float w = dinv[c];
        const float* yp = Y + (size_t)c * HH + f0;
        s0 += w * yp[0]; s1 += w * yp[1]; s2 += w * yp[2]; s3 += w * yp[3];
    }
    int f32io = flags[1];
    float b0, b1, b2, b3;
    if (f32io) {
        const float* bp = (const float*)bias + f0;
        b0 = bp[0]; b1 = bp[1]; b2 = bp[2]; b3 = bp[3];
    } else {
        const unsigned short* bp = (const unsigned short*)bias + f0;
        b0 = bf2f(bp[0]); b1 = bf2f(bp[1]); b2 = bf2f(bp[2]); b3 = bf2f(bp[3]);
    }
    float wi = dinv[i];
    float r0, r1, r2, r3;
    if (high) {
        const float* yp = Y + (size_t)i * HH + f0;
        r0 = yp[0] - wi * s0 + b0; r1 = yp[1] - wi * s1 + b1;
        r2 = yp[2] - wi * s2 + b2; r3 = yp[3] - wi * s3 + b3;
    } else {
        r0 = wi * s0 + b0; r1 = wi * s1 + b1; r2 = wi * s2 + b2; r3 = wi * s3 + b3;
    }
    if (relu) {
        r0 = fmaxf(0.f, r0); r1 = fmaxf(0.f, r1);
        r2 = fmaxf(0.f, r2); r3 = fmaxf(0.f, r3);
    }
    if (Of) {
        float* op = Of + (size_t)i * HH + f0;
        op[0] = r0; op[1] = r1; op[2] = r2; op[3] = r3;
        return;
    }
    size_t base = (size_t)i * HH + f0;
    if (f32io) {
        float* o = (float*)Oout;
        size_t p = (size_t)c0 * NN * HH + base;
        o[p] = r0; o[p + 1] = r1; o[p + 2] = r2; o[p + 3] = r3;
        if (c1 >= 0) {
            size_t q = (size_t)c1 * NN * HH + base;
            o[q] = r0; o[q + 1] = r1; o[q + 2] = r2; o[q + 3] = r3;
        }
    } else {
        unsigned short* o = (unsigned short*)Oout;
        unsigned short h0 = f2bf(r0), h1 = f2bf(r1), h2 = f2bf(r2), h3 = f2bf(r3);
        size_t p = (size_t)c0 * NN * HH + base;
        o[p] = h0; o[p + 1] = h1; o[p + 2] = h2; o[p + 3] = h3;
        if (c1 >= 0) {
            size_t q = (size_t)c1 * NN * HH + base;
            o[q] = h0; o[q + 1] = h1; o[q + 2] = h2; o[q + 3] = h3;
        }
    }
}

extern "C" void kernel_launch(void* const* d_in, const int* in_sizes, int n_in,
                              void* d_out, int out_size, void* d_ws, size_t ws_size,
                              hipStream_t stream) {
    // identify inputs by element count (robust to ordering)
    const void* x = 0; const void* ei = 0;
    const void* W1 = 0; const void* b1 = 0; const void* W2 = 0; const void* b2 = 0;
    for (int i = 0; i < n_in; i++) {
        int s = in_sizes[i];
        if (s == NN * HH) x = d_in[i];
        else if (s == 2 * EE) ei = d_in[i];
        else if (s == HH * HH) { if (!W1) W1 = d_in[i]; else W2 = d_in[i]; }
        else if (s == HH) { if (!b1) b1 = d_in[i]; else b2 = d_in[i]; }
    }

    char* ws = (char*)d_ws;
    size_t off = 0;
    int* flags = (int*)(ws + off); off += 256;
    int* rawcnt = (int*)(ws + off); off += (size_t)NN * 4;
    int* fillc = (int*)(ws + off); off += (size_t)NN * 4;
    int* deg_c = (int*)(ws + off); off += (size_t)NN * 4;
    int* deg_r = (int*)(ws + off); off += (size_t)NN * 4;
    int* row_start = (int*)(ws + off); off += (size_t)(NN + 1) * 4;
    float* dinv_r = (float*)(ws + off); off += (size_t)NN * 4;
    float* dinv_c = (float*)(ws + off); off += (size_t)NN * 4 + 256;
    int* col = (int*)(ws + off); off += (size_t)EE * 4;
    float* T1 = (float*)(ws + off); off += (size_t)NN * HH * 4;
    float* T2 = (float*)(ws + off); off += (size_t)NN * HH * 4;
    // total ~22.3 MB

    // ---- graph build
    k_detect<<<1, 64, 0, stream>>>((const unsigned int*)x, (const unsigned int*)ei, flags);
    k_zero3<<<(NN + 255) / 256, 256, 0, stream>>>(rawcnt, fillc, deg_c);
    k_count<<<EE / 256, 256, 0, stream>>>(ei, flags, rawcnt);
    k_scan<<<1, 256, 0, stream>>>(rawcnt, row_start);
    k_fill<<<EE / 256, 256, 0, stream>>>(ei, flags, row_start, fillc, col);
    k_dedup<<<NN, 64, 0, stream>>>(row_start, col, deg_r, deg_c);
    k_dinv<<<(NN + 255) / 256, 256, 0, stream>>>(deg_r, deg_c, dinv_r, dinv_c);

    // ---- low branch (anorm): z2 -> output chunks 0 and 2
    k_gemm8<<<1250, 256, 0, stream>>>(x, 0, W1, T1, NN, flags);
    k_spmm<<<NN / 4, 256, 0, stream>>>(T1, row_start, col, deg_r, dinv_c, b1, flags,
                                       0, 1, T2, 0, 0, 0);
    k_gemm8<<<1250, 256, 0, stream>>>(T2, 1, W2, T1, NN, flags);
    k_spmm<<<NN / 4, 256, 0, stream>>>(T1, row_start, col, deg_r, dinv_c, b2, flags,
                                       0, 0, 0, d_out, 0, 2);
    // ---- high branch (lsym): z1 -> output chunk 1
    k_gemm8<<<1250, 256, 0, stream>>>(x, 0, W1, T1, NN, flags);
    k_spmm<<<NN / 4, 256, 0, stream>>>(T1, row_start, col, deg_r, dinv_r, b1, flags,
                                       1, 1, T2, 0, 0, 0);
    k_gemm8<<<1250, 256, 0, stream>>>(T2, 1, W2, T1, NN, flags);
    k_spmm<<<NN / 4, 256, 0, stream>>>(T1, row_start, col, deg_r, dinv_r, b2, flags,
                                       1, 0, 0, d_out, 1, -1);
}

// Round 4
// 434.775 us; speedup vs baseline: 1.1782x; 1.1782x over previous
//
#include <hip/hip_runtime.h>

#define NN 10000
#define EE 320000
#define HH 256

__device__ float bf2f(unsigned int v) {
    return __uint_as_float(v << 16);
}
__device__ unsigned short f2bf(float f) {
    unsigned int i = __float_as_uint(f);
    return (unsigned short)((i + 0x7fffu + ((i >> 16) & 1u)) >> 16);
}

// ---- 0. Detect input dtypes. flags[0]: edge_index is int64. flags[1]: floats are f32.
__global__ void k_detect(const unsigned int* xu, const unsigned int* eu, int* flags) {
    if (threadIdx.x != 0 || blockIdx.x != 0) return;
    int odd_nonzero = 0;
    for (int k = 0; k < 256; k++) {
        if (eu[2 * k + 1] != 0) odd_nonzero = 1;
    }
    flags[0] = odd_nonzero ? 0 : 1;
    int plausible = 0;
    for (int k = 0; k < 64; k++) {
        unsigned int lo = xu[k] & 0xffffu;
        unsigned int ex = (lo >> 7) & 0xffu;
        if (lo == 0u || (ex >= 90u && ex <= 150u)) plausible++;
    }
    flags[1] = (plausible >= 56) ? 0 : 1;
}

__device__ int eload(const void* ei, int is64, int idx) {
    if (is64) return (int)(((const long long*)ei)[idx]);
    return ((const int*)ei)[idx];
}

// ---- 1. zero atomically-built arrays (ws is poisoned 0xAA each call)
__global__ void k_zero3(int* a, int* b, int* c) {
    int i = blockIdx.x * 256 + threadIdx.x;
    if (i < NN) { a[i] = 0; b[i] = 0; c[i] = 0; }
}

// ---- 2. weights -> f32 workspace copy (from bf16 or f32 per flags)
__global__ void k_wcvt(const void* w, float* o, const int* flags) {
    int i = blockIdx.x * 256 + threadIdx.x;          // grid covers 65536 exactly
    if (flags[1]) o[i] = ((const float*)w)[i];
    else          o[i] = bf2f((unsigned int)((const unsigned short*)w)[i]);
}

// ---- 3. raw per-row edge counts (duplicates included)
__global__ void k_count(const void* ei, const int* flags, int* rawcnt) {
    int e = blockIdx.x * 256 + threadIdx.x;
    if (e >= EE) return;
    int is64 = flags[0];
    int r = eload(ei, is64, e);
    int c = eload(ei, is64, EE + e);
    if (r < 0 || r >= NN || c < 0 || c >= NN) return;
    atomicAdd(&rawcnt[r], 1);
}

// ---- 4. exclusive prefix sum over rawcnt -> row_start[0..NN], single block
__global__ void k_scan(const int* cnt, int* row_start) {
    __shared__ int part[256];
    int t = threadIdx.x;
    int base = t * 40;                               // 256*40 = 10240 >= NN+1
    int s = 0;
    for (int k = 0; k < 40; k++) { int i = base + k; if (i < NN) s += cnt[i]; }
    part[t] = s;
    __syncthreads();
    for (int off = 1; off < 256; off <<= 1) {
        int add = (t >= off) ? part[t - off] : 0;
        __syncthreads();
        part[t] += add;
        __syncthreads();
    }
    int run = part[t] - s;
    for (int k = 0; k < 40; k++) {
        int i = base + k;
        if (i <= NN) row_start[i] = run;
        if (i < NN) run += cnt[i];
    }
}

// ---- 5. scatter columns into raw CSR slots (16-bit cols, NN < 65536)
__global__ void k_fill(const void* ei, const int* flags, const int* row_start,
                       int* fillc, unsigned short* col) {
    int e = blockIdx.x * 256 + threadIdx.x;
    if (e >= EE) return;
    int is64 = flags[0];
    int r = eload(ei, is64, e);
    int c = eload(ei, is64, EE + e);
    if (r < 0 || r >= NN || c < 0 || c >= NN) return;
    int pos = row_start[r] + atomicAdd(&fillc[r], 1);
    col[pos] = (unsigned short)c;
}

// ---- 6. per-row dedupe (one wave per row): compact unique cols, count degrees
__global__ void k_dedup(const int* row_start, unsigned short* col,
                        int* deg_r, int* deg_c) {
    __shared__ int lds[192];
    __shared__ int cnt;
    int i = blockIdx.x;
    int lane = threadIdx.x;
    int s = row_start[i];
    int d = row_start[i + 1] - s;
    if (d > 192) d = 192;                            // raw deg ~ Poisson(32); never hit
    if (lane == 0) cnt = 0;
    for (int t = lane; t < d; t += 64) lds[t] = (int)col[s + t];
    __syncthreads();
    for (int t = lane; t < d; t += 64) {
        int c = lds[t];
        int dup = 0;
        for (int u = 0; u < t; u++) { if (lds[u] == c) dup = 1; }
        if (!dup) {
            int p = atomicAdd(&cnt, 1);
            col[s + p] = (unsigned short)c;          // compacted unique prefix
            atomicAdd(&deg_c[c], 1);
        }
    }
    __syncthreads();
    if (lane == 0) deg_r[i] = cnt;
}

// ---- 7. dinv2[i] = (deg_r>0 ? rsqrt : 0, deg_c>0 ? rsqrt : 0) packed as float2
__global__ void k_dinv2(const int* deg_r, const int* deg_c, float* dinv2) {
    int i = blockIdx.x * 256 + threadIdx.x;
    if (i >= NN) return;
    int dr = deg_r[i], dc = deg_c[i];
    dinv2[2 * i]     = dr > 0 ? rsqrtf((float)dr) : 0.0f;
    dinv2[2 * i + 1] = dc > 0 ? rsqrtf((float)dc) : 0.0f;
}

// ---- 8. GEMM: C[r*cstride + coffs + c](bf16) = A[M x 256] @ B[256 x 256](f32).
//  amode=0: A is input x (dtype per flags[1]); amode=1: A is bf16 workspace.
//  Block: 256 thr = 4 waves; tile 32 rows x 256 cols; thread owns 8 rows x 4 cols.
__global__ void k_gemm32(const void* A, int amode, const float* B,
                         unsigned short* C, int M, int cstride, int coffs,
                         const int* flags) {
    __shared__ float As[32][256];
    int t = threadIdx.x;
    int r0 = blockIdx.x * 32;
    int af32 = amode ? 0 : flags[1];
    for (int idx = t; idx < 32 * 256; idx += 256) {
        int r = r0 + (idx >> 8);
        int k = idx & 255;
        float v = 0.0f;
        if (r < M) {
            if (af32) v = ((const float*)A)[(size_t)r * HH + k];
            else      v = bf2f((unsigned int)((const unsigned short*)A)[(size_t)r * HH + k]);
        }
        As[idx >> 8][k] = v;
    }
    __syncthreads();
    int cg = (t & 63) * 4;
    int rg = (t >> 6) * 8;
    float acc[8][4];
    #pragma unroll
    for (int j = 0; j < 8; j++)
        for (int c = 0; c < 4; c++) acc[j][c] = 0.0f;
    for (int k = 0; k < 256; k++) {
        float4 bv = *(const float4*)(B + (size_t)k * HH + cg);
        #pragma unroll
        for (int j = 0; j < 8; j++) {
            float a = As[rg + j][k];
            acc[j][0] += a * bv.x;
            acc[j][1] += a * bv.y;
            acc[j][2] += a * bv.z;
            acc[j][3] += a * bv.w;
        }
    }
    for (int j = 0; j < 8; j++) {
        int r = r0 + rg + j;
        if (r >= M) break;
        uint2 pv;
        pv.x = (unsigned int)f2bf(acc[j][0]) | ((unsigned int)f2bf(acc[j][1]) << 16);
        pv.y = (unsigned int)f2bf(acc[j][2]) | ((unsigned int)f2bf(acc[j][3]) << 16);
        *(uint2*)(C + (size_t)r * cstride + coffs + cg) = pv;
    }
}

// ---- 9. Fused mid layer: ONE gather of Y feeds both branches.
//  h1 = relu(Y[i] - wr_i*Sum(wr_j*Y[j]) + b1), h2 = relu(wc_i*Sum(wc_j*Y[j]) + b1)
__global__ void k_spmm_mid(const unsigned short* Y, const int* row_start,
                           const unsigned short* col, const int* ucnt,
                           const float* dinv2, const void* bias, const int* flags,
                           unsigned short* H1, unsigned short* H2) {
    int wave = threadIdx.x >> 6;
    int lane = threadIdx.x & 63;
    int i = blockIdx.x * 4 + wave;                   // grid = NN/4 exactly
    int f0 = lane * 4;
    float r0 = 0.f, r1 = 0.f, r2 = 0.f, r3 = 0.f;
    float c0 = 0.f, c1 = 0.f, c2 = 0.f, c3 = 0.f;
    int s = row_start[i];
    int e = s + ucnt[i];
    for (int t = s; t < e; t++) {
        int c = (int)col[t];
        float2 w = *(const float2*)(dinv2 + 2 * c);
        uint2 raw = *(const uint2*)(Y + (size_t)c * HH + f0);
        float y0 = __uint_as_float(raw.x << 16);
        float y1 = __uint_as_float(raw.x & 0xffff0000u);
        float y2 = __uint_as_float(raw.y << 16);
        float y3 = __uint_as_float(raw.y & 0xffff0000u);
        r0 += w.x * y0; r1 += w.x * y1; r2 += w.x * y2; r3 += w.x * y3;
        c0 += w.y * y0; c1 += w.y * y1; c2 += w.y * y2; c3 += w.y * y3;
    }
    float b0, b1, b2, b3;
    if (flags[1]) {
        const float* bp = (const float*)bias + f0;
        b0 = bp[0]; b1 = bp[1]; b2 = bp[2]; b3 = bp[3];
    } else {
        const unsigned short* bp = (const unsigned short*)bias + f0;
        b0 = bf2f(bp[0]); b1 = bf2f(bp[1]); b2 = bf2f(bp[2]); b3 = bf2f(bp[3]);
    }
    float2 wi = *(const float2*)(dinv2 + 2 * i);
    uint2 yr = *(const uint2*)(Y + (size_t)i * HH + f0);
    float yi0 = __uint_as_float(yr.x << 16);
    float yi1 = __uint_as_float(yr.x & 0xffff0000u);
    float yi2 = __uint_as_float(yr.y << 16);
    float yi3 = __uint_as_float(yr.y & 0xffff0000u);
    float h10 = fmaxf(0.f, yi0 - wi.x * r0 + b0);
    float h11 = fmaxf(0.f, yi1 - wi.x * r1 + b1);
    float h12 = fmaxf(0.f, yi2 - wi.x * r2 + b2);
    float h13 = fmaxf(0.f, yi3 - wi.x * r3 + b3);
    float h20 = fmaxf(0.f, wi.y * c0 + b0);
    float h21 = fmaxf(0.f, wi.y * c1 + b1);
    float h22 = fmaxf(0.f, wi.y * c2 + b2);
    float h23 = fmaxf(0.f, wi.y * c3 + b3);
    uint2 p1, p2;
    p1.x = (unsigned int)f2bf(h10) | ((unsigned int)f2bf(h11) << 16);
    p1.y = (unsigned int)f2bf(h12) | ((unsigned int)f2bf(h13) << 16);
    p2.x = (unsigned int)f2bf(h20) | ((unsigned int)f2bf(h21) << 16);
    p2.y = (unsigned int)f2bf(h22) | ((unsigned int)f2bf(h23) << 16);
    *(uint2*)(H1 + (size_t)i * HH + f0) = p1;
    *(uint2*)(H2 + (size_t)i * HH + f0) = p2;
}

// ---- 10. Fused final layer. G12 rows hold [G1(256) | G2(256)] interleaved.
//  z1 = G1[i] - wr_i*Sum(wr_j*G1[j]) + b2 -> chunk 1
//  z2 = wc_i*Sum(wc_j*G2[j]) + b2        -> chunks 0 and 2
__global__ void k_spmm_fin(const unsigned short* G12, const int* row_start,
                           const unsigned short* col, const int* ucnt,
                           const float* dinv2, const void* bias, const int* flags,
                           void* Oout) {
    int wave = threadIdx.x >> 6;
    int lane = threadIdx.x & 63;
    int i = blockIdx.x * 4 + wave;
    int f0 = lane * 4;
    float r0 = 0.f, r1 = 0.f, r2 = 0.f, r3 = 0.f;
    float c0 = 0.f, c1 = 0.f, c2 = 0.f, c3 = 0.f;
    int s = row_start[i];
    int e = s + ucnt[i];
    for (int t = s; t < e; t++) {
        int c = (int)col[t];
        float2 w = *(const float2*)(dinv2 + 2 * c);
        uint2 g1 = *(const uint2*)(G12 + (size_t)c * 512 + f0);
        uint2 g2 = *(const uint2*)(G12 + (size_t)c * 512 + 256 + f0);
        r0 += w.x * __uint_as_float(g1.x << 16);
        r1 += w.x * __uint_as_float(g1.x & 0xffff0000u);
        r2 += w.x * __uint_as_float(g1.y << 16);
        r3 += w.x * __uint_as_float(g1.y & 0xffff0000u);
        c0 += w.y * __uint_as_float(g2.x << 16);
        c1 += w.y * __uint_as_float(g2.x & 0xffff0000u);
        c2 += w.y * __uint_as_float(g2.y << 16);
        c3 += w.y * __uint_as_float(g2.y & 0xffff0000u);
    }
    float b0, b1, b2, b3;
    int f32io = flags[1];
    if (f32io) {
        const float* bp = (const float*)bias + f0;
        b0 = bp[0]; b1 = bp[1]; b2 = bp[2]; b3 = bp[3];
    } else {
        const unsigned short* bp = (const unsigned short*)bias + f0;
        b0 = bf2f(bp[0]); b1 = bf2f(bp[1]); b2 = bf2f(bp[2]); b3 = bf2f(bp[3]);
    }
    float2 wi = *(const float2*)(dinv2 + 2 * i);
    uint2 gi = *(const uint2*)(G12 + (size_t)i * 512 + f0);
    float z10 = __uint_as_float(gi.x << 16)         - wi.x * r0 + b0;
    float z11 = __uint_as_float(gi.x & 0xffff0000u) - wi.x * r1 + b1;
    float z12 = __uint_as_float(gi.y << 16)         - wi.x * r2 + b2;
    float z13 = __uint_as_float(gi.y & 0xffff0000u) - wi.x * r3 + b3;
    float z20 = wi.y * c0 + b0;
    float z21 = wi.y * c1 + b1;
    float z22 = wi.y * c2 + b2;
    float z23 = wi.y * c3 + b3;
    size_t base = (size_t)i * HH + f0;
    size_t chunk = (size_t)NN * HH;
    if (f32io) {
        float* o = (float*)Oout;
        o[base] = z20; o[base + 1] = z21; o[base + 2] = z22; o[base + 3] = z23;
        o[chunk + base] = z10; o[chunk + base + 1] = z11;
        o[chunk + base + 2] = z12; o[chunk + base + 3] = z13;
        o[2 * chunk + base] = z20; o[2 * chunk + base + 1] = z21;
        o[2 * chunk + base + 2] = z22; o[2 * chunk + base + 3] = z23;
    } else {
        unsigned short* o = (unsigned short*)Oout;
        uint2 p1, p2;
        p1.x = (unsigned int)f2bf(z10) | ((unsigned int)f2bf(z11) << 16);
        p1.y = (unsigned int)f2bf(z12) | ((unsigned int)f2bf(z13) << 16);
        p2.x = (unsigned int)f2bf(z20) | ((unsigned int)f2bf(z21) << 16);
        p2.y = (unsigned int)f2bf(z22) | ((unsigned int)f2bf(z23) << 16);
        *(uint2*)(o + base) = p2;
        *(uint2*)(o + chunk + base) = p1;
        *(uint2*)(o + 2 * chunk + base) = p2;
    }
}

extern "C" void kernel_launch(void* const* d_in, const int* in_sizes, int n_in,
                              void* d_out, int out_size, void* d_ws, size_t ws_size,
                              hipStream_t stream) {
    const void* x = 0; const void* ei = 0;
    const void* W1 = 0; const void* b1 = 0; const void* W2 = 0; const void* b2 = 0;
    for (int i = 0; i < n_in; i++) {
        int s = in_sizes[i];
        if (s == NN * HH) x = d_in[i];
        else if (s == 2 * EE) ei = d_in[i];
        else if (s == HH * HH) { if (!W1) W1 = d_in[i]; else W2 = d_in[i]; }
        else if (s == HH) { if (!b1) b1 = d_in[i]; else b2 = d_in[i]; }
    }

    char* ws = (char*)d_ws;
    size_t off = 0;
    int* flags = (int*)(ws + off); off += 256;
    int* rawcnt = (int*)(ws + off); off += (size_t)NN * 4;
    int* fillc = (int*)(ws + off); off += (size_t)NN * 4;
    int* deg_c = (int*)(ws + off); off += (size_t)NN * 4;
    int* deg_r = (int*)(ws + off); off += (size_t)NN * 4;       // = unique count per row
    int* row_start = (int*)(ws + off); off += (size_t)(NN + 4) * 4;
    float* dinv2 = (float*)(ws + off); off += (size_t)NN * 8;
    unsigned short* col = (unsigned short*)(ws + off); off += (size_t)EE * 2;
    float* W1f = (float*)(ws + off); off += (size_t)HH * HH * 4;
    float* W2f = (float*)(ws + off); off += (size_t)HH * HH * 4;
    unsigned short* G12 = (unsigned short*)(ws + off); off += (size_t)NN * 512 * 2;
    unsigned short* Y = G12;                                     // aliases G12 (dead before G12 written)
    unsigned short* H1 = (unsigned short*)(ws + off); off += (size_t)NN * HH * 2;
    unsigned short* H2 = (unsigned short*)(ws + off); off += (size_t)NN * HH * 2;
    // total ~21.9 MB (<= round-3's proven 22.3 MB)

    // ---- graph build
    k_detect<<<1, 64, 0, stream>>>((const unsigned int*)x, (const unsigned int*)ei, flags);
    k_zero3<<<(NN + 255) / 256, 256, 0, stream>>>(rawcnt, fillc, deg_c);
    k_wcvt<<<HH * HH / 256, 256, 0, stream>>>(W1, W1f, flags);
    k_wcvt<<<HH * HH / 256, 256, 0, stream>>>(W2, W2f, flags);
    k_count<<<EE / 256, 256, 0, stream>>>(ei, flags, rawcnt);
    k_scan<<<1, 256, 0, stream>>>(rawcnt, row_start);
    k_fill<<<EE / 256, 256, 0, stream>>>(ei, flags, row_start, fillc, col);
    k_dedup<<<NN, 64, 0, stream>>>(row_start, col, deg_r, deg_c);
    k_dinv2<<<(NN + 255) / 256, 256, 0, stream>>>(deg_r, deg_c, dinv2);

    // ---- Y = x @ W1 (shared by both branches)
    k_gemm32<<<(NN + 31) / 32, 256, 0, stream>>>(x, 0, W1f, Y, NN, HH, 0, flags);
    // ---- fused mid layer: h1 (lsym) and h2 (anorm) from one gather of Y
    k_spmm_mid<<<NN / 4, 256, 0, stream>>>(Y, row_start, col, deg_r, dinv2, b1, flags, H1, H2);
    // ---- G1 = h1 @ W2, G2 = h2 @ W2, interleaved rows in G12 (overwrites dead Y)
    k_gemm32<<<(NN + 31) / 32, 256, 0, stream>>>(H1, 1, W2f, G12, NN, 512, 0, flags);
    k_gemm32<<<(NN + 31) / 32, 256, 0, stream>>>(H2, 1, W2f, G12, NN, 512, 256, flags);
    // ---- fused final layer + all three output chunks
    k_spmm_fin<<<NN / 4, 256, 0, stream>>>(G12, row_start, col, deg_r, dinv2, b2, flags, d_out);
}

// Round 5
// 324.165 us; speedup vs baseline: 1.5802x; 1.3412x over previous
//
#include <hip/hip_runtime.h>

#define NN 10000
#define EE 320000
#define HH 256

__device__ float bf2f(unsigned int v) {
    return __uint_as_float(v << 16);
}
__device__ unsigned short f2bf(float f) {
    unsigned int i = __float_as_uint(f);
    return (unsigned short)((i + 0x7fffu + ((i >> 16) & 1u)) >> 16);
}

// ---- 0. Detect input dtypes (parallel). flags[0]: edge_index int64. flags[1]: floats f32.
__global__ void k_detect(const unsigned int* xu, const unsigned int* eu, int* flags) {
    __shared__ int odd_nz;
    __shared__ int plaus;
    int t = threadIdx.x;
    if (t == 0) { odd_nz = 0; plaus = 0; }
    __syncthreads();
    for (int k = t; k < 256; k += 64) {
        if (eu[2 * k + 1] != 0) atomicOr(&odd_nz, 1);
    }
    unsigned int lo = xu[t] & 0xffffu;
    unsigned int ex = (lo >> 7) & 0xffu;
    if (lo == 0u || (ex >= 90u && ex <= 150u)) atomicAdd(&plaus, 1);
    __syncthreads();
    if (t == 0) {
        flags[0] = odd_nz ? 0 : 1;
        flags[1] = (plaus >= 56) ? 0 : 1;
    }
}

__device__ int eload(const void* ei, int is64, int idx) {
    if (is64) return (int)(((const long long*)ei)[idx]);
    return ((const int*)ei)[idx];
}

// ---- 1. zero atomically-built arrays (ws is poisoned 0xAA each call)
__global__ void k_zero3(int* a, int* b, int* c) {
    int i = blockIdx.x * 256 + threadIdx.x;
    if (i < NN) { a[i] = 0; b[i] = 0; c[i] = 0; }
}

// ---- 2. weights -> f32 workspace copy
__global__ void k_wcvt(const void* w, float* o, const int* flags) {
    int i = blockIdx.x * 256 + threadIdx.x;          // grid covers 65536 exactly
    if (flags[1]) o[i] = ((const float*)w)[i];
    else          o[i] = bf2f((unsigned int)((const unsigned short*)w)[i]);
}

// ---- 3. raw per-row edge counts (duplicates included)
__global__ void k_count(const void* ei, const int* flags, int* rawcnt) {
    int e = blockIdx.x * 256 + threadIdx.x;
    if (e >= EE) return;
    int is64 = flags[0];
    int r = eload(ei, is64, e);
    int c = eload(ei, is64, EE + e);
    if (r < 0 || r >= NN || c < 0 || c >= NN) return;
    atomicAdd(&rawcnt[r], 1);
}

// ---- 4. exclusive prefix sum over rawcnt -> row_start[0..NN], single block
__global__ void k_scan(const int* cnt, int* row_start) {
    __shared__ int part[256];
    int t = threadIdx.x;
    int base = t * 40;                               // 256*40 = 10240 >= NN+1
    int s = 0;
    for (int k = 0; k < 40; k++) { int i = base + k; if (i < NN) s += cnt[i]; }
    part[t] = s;
    __syncthreads();
    for (int off = 1; off < 256; off <<= 1) {
        int add = (t >= off) ? part[t - off] : 0;
        __syncthreads();
        part[t] += add;
        __syncthreads();
    }
    int run = part[t] - s;
    for (int k = 0; k < 40; k++) {
        int i = base + k;
        if (i <= NN) row_start[i] = run;
        if (i < NN) run += cnt[i];
    }
}

// ---- 5. scatter columns into raw CSR slots (16-bit cols, NN < 65536)
__global__ void k_fill(const void* ei, const int* flags, const int* row_start,
                       int* fillc, unsigned short* col) {
    int e = blockIdx.x * 256 + threadIdx.x;
    if (e >= EE) return;
    int is64 = flags[0];
    int r = eload(ei, is64, e);
    int c = eload(ei, is64, EE + e);
    if (r < 0 || r >= NN || c < 0 || c >= NN) return;
    int pos = row_start[r] + atomicAdd(&fillc[r], 1);
    col[pos] = (unsigned short)c;
}

// ---- 6. per-row dedupe (one wave per row): compact unique cols, count degrees
__global__ void k_dedup(const int* row_start, unsigned short* col,
                        int* deg_r, int* deg_c) {
    __shared__ int lds[192];
    __shared__ int cnt;
    int i = blockIdx.x;
    int lane = threadIdx.x;
    int s = row_start[i];
    int d = row_start[i + 1] - s;
    if (d > 192) d = 192;                            // raw deg ~ Poisson(32); never hit
    if (lane == 0) cnt = 0;
    for (int t = lane; t < d; t += 64) lds[t] = (int)col[s + t];
    __syncthreads();
    for (int t = lane; t < d; t += 64) {
        int c = lds[t];
        int dup = 0;
        for (int u = 0; u < t; u++) { if (lds[u] == c) dup = 1; }
        if (!dup) {
            int p = atomicAdd(&cnt, 1);
            col[s + p] = (unsigned short)c;          // compacted unique prefix
            atomicAdd(&deg_c[c], 1);
        }
    }
    __syncthreads();
    if (lane == 0) deg_r[i] = cnt;
}

// ---- 7. dinv2[i] = (rsqrt(deg_r) | 0, rsqrt(deg_c) | 0) packed float2
__global__ void k_dinv2(const int* deg_r, const int* deg_c, float* dinv2) {
    int i = blockIdx.x * 256 + threadIdx.x;
    if (i >= NN) return;
    int dr = deg_r[i], dc = deg_c[i];
    dinv2[2 * i]     = dr > 0 ? rsqrtf((float)dr) : 0.0f;
    dinv2[2 * i + 1] = dc > 0 ? rsqrtf((float)dc) : 0.0f;
}

// ---- 8. GEMM (Y = x @ W1): tile 16 rows x 256 cols, thread = 4 rows x 4 cols.
//  grid = 625 (16*625 = 10000 exact). A dtype per flags (input x).
__global__ void k_gemm16(const void* A, const float* B, unsigned short* C,
                         const int* flags) {
    __shared__ float As[16][256];
    int t = threadIdx.x;
    int r0 = blockIdx.x * 16;
    int af32 = flags[1];
    for (int idx = t; idx < 16 * 256; idx += 256) {
        int r = r0 + (idx >> 8);
        int k = idx & 255;
        float v;
        if (af32) v = ((const float*)A)[(size_t)r * HH + k];
        else      v = bf2f((unsigned int)((const unsigned short*)A)[(size_t)r * HH + k]);
        As[idx >> 8][k] = v;
    }
    __syncthreads();
    int cg = (t & 63) * 4;
    int rg = (t >> 6) * 4;
    float acc[4][4];
    #pragma unroll
    for (int j = 0; j < 4; j++)
        for (int c = 0; c < 4; c++) acc[j][c] = 0.0f;
    for (int k = 0; k < 256; k += 2) {
        float4 bv0 = *(const float4*)(B + (size_t)k * HH + cg);
        float4 bv1 = *(const float4*)(B + (size_t)(k + 1) * HH + cg);
        float a0 = As[rg][k],     a1 = As[rg + 1][k];
        float a2 = As[rg + 2][k], a3 = As[rg + 3][k];
        float d0 = As[rg][k + 1],     d1 = As[rg + 1][k + 1];
        float d2 = As[rg + 2][k + 1], d3 = As[rg + 3][k + 1];
        acc[0][0] += a0 * bv0.x; acc[0][1] += a0 * bv0.y; acc[0][2] += a0 * bv0.z; acc[0][3] += a0 * bv0.w;
        acc[1][0] += a1 * bv0.x; acc[1][1] += a1 * bv0.y; acc[1][2] += a1 * bv0.z; acc[1][3] += a1 * bv0.w;
        acc[2][0] += a2 * bv0.x; acc[2][1] += a2 * bv0.y; acc[2][2] += a2 * bv0.z; acc[2][3] += a2 * bv0.w;
        acc[3][0] += a3 * bv0.x; acc[3][1] += a3 * bv0.y; acc[3][2] += a3 * bv0.z; acc[3][3] += a3 * bv0.w;
        acc[0][0] += d0 * bv1.x; acc[0][1] += d0 * bv1.y; acc[0][2] += d0 * bv1.z; acc[0][3] += d0 * bv1.w;
        acc[1][0] += d1 * bv1.x; acc[1][1] += d1 * bv1.y; acc[1][2] += d1 * bv1.z; acc[1][3] += d1 * bv1.w;
        acc[2][0] += d2 * bv1.x; acc[2][1] += d2 * bv1.y; acc[2][2] += d2 * bv1.z; acc[2][3] += d2 * bv1.w;
        acc[3][0] += d3 * bv1.x; acc[3][1] += d3 * bv1.y; acc[3][2] += d3 * bv1.z; acc[3][3] += d3 * bv1.w;
    }
    for (int j = 0; j < 4; j++) {
        int r = r0 + rg + j;
        uint2 pv;
        pv.x = (unsigned int)f2bf(acc[j][0]) | ((unsigned int)f2bf(acc[j][1]) << 16);
        pv.y = (unsigned int)f2bf(acc[j][2]) | ((unsigned int)f2bf(acc[j][3]) << 16);
        *(uint2*)(C + (size_t)r * HH + cg) = pv;
    }
}

// ---- 9. Merged G-GEMM: blocks [0,625) do G1 = H1@W2 -> G12[:, 0:256];
//          blocks [625,1250) do G2 = H2@W2 -> G12[:, 256:512]. A is bf16.
__global__ void k_gemmG(const unsigned short* H1, const unsigned short* H2,
                        const float* B, unsigned short* G12) {
    __shared__ float As[16][256];
    int t = threadIdx.x;
    int b = blockIdx.x;
    const unsigned short* A = (b < 625) ? H1 : H2;
    int coffs = (b < 625) ? 0 : 256;
    int r0 = ((b < 625) ? b : b - 625) * 16;
    for (int idx = t; idx < 16 * 256; idx += 256) {
        int r = r0 + (idx >> 8);
        int k = idx & 255;
        As[idx >> 8][k] = bf2f((unsigned int)A[(size_t)r * HH + k]);
    }
    __syncthreads();
    int cg = (t & 63) * 4;
    int rg = (t >> 6) * 4;
    float acc[4][4];
    #pragma unroll
    for (int j = 0; j < 4; j++)
        for (int c = 0; c < 4; c++) acc[j][c] = 0.0f;
    for (int k = 0; k < 256; k += 2) {
        float4 bv0 = *(const float4*)(B + (size_t)k * HH + cg);
        float4 bv1 = *(const float4*)(B + (size_t)(k + 1) * HH + cg);
        float a0 = As[rg][k],     a1 = As[rg + 1][k];
        float a2 = As[rg + 2][k], a3 = As[rg + 3][k];
        float d0 = As[rg][k + 1],     d1 = As[rg + 1][k + 1];
        float d2 = As[rg + 2][k + 1], d3 = As[rg + 3][k + 1];
        acc[0][0] += a0 * bv0.x; acc[0][1] += a0 * bv0.y; acc[0][2] += a0 * bv0.z; acc[0][3] += a0 * bv0.w;
        acc[1][0] += a1 * bv0.x; acc[1][1] += a1 * bv0.y; acc[1][2] += a1 * bv0.z; acc[1][3] += a1 * bv0.w;
        acc[2][0] += a2 * bv0.x; acc[2][1] += a2 * bv0.y; acc[2][2] += a2 * bv0.z; acc[2][3] += a2 * bv0.w;
        acc[3][0] += a3 * bv0.x; acc[3][1] += a3 * bv0.y; acc[3][2] += a3 * bv0.z; acc[3][3] += a3 * bv0.w;
        acc[0][0] += d0 * bv1.x; acc[0][1] += d0 * bv1.y; acc[0][2] += d0 * bv1.z; acc[0][3] += d0 * bv1.w;
        acc[1][0] += d1 * bv1.x; acc[1][1] += d1 * bv1.y; acc[1][2] += d1 * bv1.z; acc[1][3] += d1 * bv1.w;
        acc[2][0] += d2 * bv1.x; acc[2][1] += d2 * bv1.y; acc[2][2] += d2 * bv1.z; acc[2][3] += d2 * bv1.w;
        acc[3][0] += d3 * bv1.x; acc[3][1] += d3 * bv1.y; acc[3][2] += d3 * bv1.z; acc[3][3] += d3 * bv1.w;
    }
    for (int j = 0; j < 4; j++) {
        int r = r0 + rg + j;
        uint2 pv;
        pv.x = (unsigned int)f2bf(acc[j][0]) | ((unsigned int)f2bf(acc[j][1]) << 16);
        pv.y = (unsigned int)f2bf(acc[j][2]) | ((unsigned int)f2bf(acc[j][3]) << 16);
        *(uint2*)(G12 + (size_t)r * 512 + coffs + cg) = pv;
    }
}

// ---- 10. Fused mid layer, edge loop unrolled x4 for memory-level parallelism.
__global__ void k_spmm_mid(const unsigned short* Y, const int* row_start,
                           const unsigned short* col, const int* ucnt,
                           const float* dinv2, const void* bias, const int* flags,
                           unsigned short* H1, unsigned short* H2) {
    int wave = threadIdx.x >> 6;
    int lane = threadIdx.x & 63;
    int i = blockIdx.x * 4 + wave;                   // grid = NN/4 exactly
    int f0 = lane * 4;
    float r0 = 0.f, r1 = 0.f, r2 = 0.f, r3 = 0.f;
    float c0 = 0.f, c1 = 0.f, c2 = 0.f, c3 = 0.f;
    int s = row_start[i];
    int e = s + ucnt[i];
    int e4 = s + ((e - s) & ~3);
    int t = s;
    for (; t < e4; t += 4) {
        int ca = (int)col[t];
        int cb = (int)col[t + 1];
        int cc = (int)col[t + 2];
        int cd = (int)col[t + 3];
        float2 wa = *(const float2*)(dinv2 + 2 * ca);
        float2 wb = *(const float2*)(dinv2 + 2 * cb);
        float2 wc = *(const float2*)(dinv2 + 2 * cc);
        float2 wd = *(const float2*)(dinv2 + 2 * cd);
        uint2 ya = *(const uint2*)(Y + (size_t)ca * HH + f0);
        uint2 yb = *(const uint2*)(Y + (size_t)cb * HH + f0);
        uint2 yc = *(const uint2*)(Y + (size_t)cc * HH + f0);
        uint2 yd = *(const uint2*)(Y + (size_t)cd * HH + f0);
        float y0, y1, y2, y3;
        y0 = __uint_as_float(ya.x << 16); y1 = __uint_as_float(ya.x & 0xffff0000u);
        y2 = __uint_as_float(ya.y << 16); y3 = __uint_as_float(ya.y & 0xffff0000u);
        r0 += wa.x * y0; r1 += wa.x * y1; r2 += wa.x * y2; r3 += wa.x * y3;
        c0 += wa.y * y0; c1 += wa.y * y1; c2 += wa.y * y2; c3 += wa.y * y3;
        y0 = __uint_as_float(yb.x << 16); y1 = __uint_as_float(yb.x & 0xffff0000u);
        y2 = __uint_as_float(yb.y << 16); y3 = __uint_as_float(yb.y & 0xffff0000u);
        r0 += wb.x * y0; r1 += wb.x * y1; r2 += wb.x * y2; r3 += wb.x * y3;
        c0 += wb.y * y0; c1 += wb.y * y1; c2 += wb.y * y2; c3 += wb.y * y3;
        y0 = __uint_as_float(yc.x << 16); y1 = __uint_as_float(yc.x & 0xffff0000u);
        y2 = __uint_as_float(yc.y << 16); y3 = __uint_as_float(yc.y & 0xffff0000u);
        r0 += wc.x * y0; r1 += wc.x * y1; r2 += wc.x * y2; r3 += wc.x * y3;
        c0 += wc.y * y0; c1 += wc.y * y1; c2 += wc.y * y2; c3 += wc.y * y3;
        y0 = __uint_as_float(yd.x << 16); y1 = __uint_as_float(yd.x & 0xffff0000u);
        y2 = __uint_as_float(yd.y << 16); y3 = __uint_as_float(yd.y & 0xffff0000u);
        r0 += wd.x * y0; r1 += wd.x * y1; r2 += wd.x * y2; r3 += wd.x * y3;
        c0 += wd.y * y0; c1 += wd.y * y1; c2 += wd.y * y2; c3 += wd.y * y3;
    }
    for (; t < e; t++) {
        int c = (int)col[t];
        float2 w = *(const float2*)(dinv2 + 2 * c);
        uint2 raw = *(const uint2*)(Y + (size_t)c * HH + f0);
        float y0 = __uint_as_float(raw.x << 16);
        float y1 = __uint_as_float(raw.x & 0xffff0000u);
        float y2 = __uint_as_float(raw.y << 16);
        float y3 = __uint_as_float(raw.y & 0xffff0000u);
        r0 += w.x * y0; r1 += w.x * y1; r2 += w.x * y2; r3 += w.x * y3;
        c0 += w.y * y0; c1 += w.y * y1; c2 += w.y * y2; c3 += w.y * y3;
    }
    float b0, b1, b2, b3;
    if (flags[1]) {
        const float* bp = (const float*)bias + f0;
        b0 = bp[0]; b1 = bp[1]; b2 = bp[2]; b3 = bp[3];
    } else {
        const unsigned short* bp = (const unsigned short*)bias + f0;
        b0 = bf2f(bp[0]); b1 = bf2f(bp[1]); b2 = bf2f(bp[2]); b3 = bf2f(bp[3]);
    }
    float2 wi = *(const float2*)(dinv2 + 2 * i);
    uint2 yr = *(const uint2*)(Y + (size_t)i * HH + f0);
    float yi0 = __uint_as_float(yr.x << 16);
    float yi1 = __uint_as_float(yr.x & 0xffff0000u);
    float yi2 = __uint_as_float(yr.y << 16);
    float yi3 = __uint_as_float(yr.y & 0xffff0000u);
    float h10 = fmaxf(0.f, yi0 - wi.x * r0 + b0);
    float h11 = fmaxf(0.f, yi1 - wi.x * r1 + b1);
    float h12 = fmaxf(0.f, yi2 - wi.x * r2 + b2);
    float h13 = fmaxf(0.f, yi3 - wi.x * r3 + b3);
    float h20 = fmaxf(0.f, wi.y * c0 + b0);
    float h21 = fmaxf(0.f, wi.y * c1 + b1);
    float h22 = fmaxf(0.f, wi.y * c2 + b2);
    float h23 = fmaxf(0.f, wi.y * c3 + b3);
    uint2 p1, p2;
    p1.x = (unsigned int)f2bf(h10) | ((unsigned int)f2bf(h11) << 16);
    p1.y = (unsigned int)f2bf(h12) | ((unsigned int)f2bf(h13) << 16);
    p2.x = (unsigned int)f2bf(h20) | ((unsigned int)f2bf(h21) << 16);
    p2.y = (unsigned int)f2bf(h22) | ((unsigned int)f2bf(h23) << 16);
    *(uint2*)(H1 + (size_t)i * HH + f0) = p1;
    *(uint2*)(H2 + (size_t)i * HH + f0) = p2;
}

// ---- 11. Fused final layer, edge loop unrolled x4.
__global__ void k_spmm_fin(const unsigned short* G12, const int* row_start,
                           const unsigned short* col, const int* ucnt,
                           const float* dinv2, const void* bias, const int* flags,
                           void* Oout) {
    int wave = threadIdx.x >> 6;
    int lane = threadIdx.x & 63;
    int i = blockIdx.x * 4 + wave;
    int f0 = lane * 4;
    float r0 = 0.f, r1 = 0.f, r2 = 0.f, r3 = 0.f;
    float c0 = 0.f, c1 = 0.f, c2 = 0.f, c3 = 0.f;
    int s = row_start[i];
    int e = s + ucnt[i];
    int e4 = s + ((e - s) & ~3);
    int t = s;
    for (; t < e4; t += 4) {
        int ca = (int)col[t];
        int cb = (int)col[t + 1];
        int cc = (int)col[t + 2];
        int cd = (int)col[t + 3];
        float2 wa = *(const float2*)(dinv2 + 2 * ca);
        float2 wb = *(const float2*)(dinv2 + 2 * cb);
        float2 wc = *(const float2*)(dinv2 + 2 * cc);
        float2 wd = *(const float2*)(dinv2 + 2 * cd);
        uint2 g1a = *(const uint2*)(G12 + (size_t)ca * 512 + f0);
        uint2 g2a = *(const uint2*)(G12 + (size_t)ca * 512 + 256 + f0);
        uint2 g1b = *(const uint2*)(G12 + (size_t)cb * 512 + f0);
        uint2 g2b = *(const uint2*)(G12 + (size_t)cb * 512 + 256 + f0);
        uint2 g1c = *(const uint2*)(G12 + (size_t)cc * 512 + f0);
        uint2 g2c = *(const uint2*)(G12 + (size_t)cc * 512 + 256 + f0);
        uint2 g1d = *(const uint2*)(G12 + (size_t)cd * 512 + f0);
        uint2 g2d = *(const uint2*)(G12 + (size_t)cd * 512 + 256 + f0);
        r0 += wa.x * __uint_as_float(g1a.x << 16);
        r1 += wa.x * __uint_as_float(g1a.x & 0xffff0000u);
        r2 += wa.x * __uint_as_float(g1a.y << 16);
        r3 += wa.x * __uint_as_float(g1a.y & 0xffff0000u);
        c0 += wa.y * __uint_as_float(g2a.x << 16);
        c1 += wa.y * __uint_as_float(g2a.x & 0xffff0000u);
        c2 += wa.y * __uint_as_float(g2a.y << 16);
        c3 += wa.y * __uint_as_float(g2a.y & 0xffff0000u);
        r0 += wb.x * __uint_as_float(g1b.x << 16);
        r1 += wb.x * __uint_as_float(g1b.x & 0xffff0000u);
        r2 += wb.x * __uint_as_float(g1b.y << 16);
        r3 += wb.x * __uint_as_float(g1b.y & 0xffff0000u);
        c0 += wb.y * __uint_as_float(g2b.x << 16);
        c1 += wb.y * __uint_as_float(g2b.x & 0xffff0000u);
        c2 += wb.y * __uint_as_float(g2b.y << 16);
        c3 += wb.y * __uint_as_float(g2b.y & 0xffff0000u);
        r0 += wc.x * __uint_as_float(g1c.x << 16);
        r1 += wc.x * __uint_as_float(g1c.x & 0xffff0000u);
        r2 += wc.x * __uint_as_float(g1c.y << 16);
        r3 += wc.x * __uint_as_float(g1c.y & 0xffff0000u);
        c0 += wc.y * __uint_as_float(g2c.x << 16);
        c1 += wc.y * __uint_as_float(g2c.x & 0xffff0000u);
        c2 += wc.y * __uint_as_float(g2c.y << 16);
        c3 += wc.y * __uint_as_float(g2c.y & 0xffff0000u);
        r0 += wd.x * __uint_as_float(g1d.x << 16);
        r1 += wd.x * __uint_as_float(g1d.x & 0xffff0000u);
        r2 += wd.x * __uint_as_float(g1d.y << 16);
        r3 += wd.x * __uint_as_float(g1d.y & 0xffff0000u);
        c0 += wd.y * __uint_as_float(g2d.x << 16);
        c1 += wd.y * __uint_as_float(g2d.x & 0xffff0000u);
        c2 += wd.y * __uint_as_float(g2d.y << 16);
        c3 += wd.y * __uint_as_float(g2d.y & 0xffff0000u);
    }
    for (; t < e; t++) {
        int c = (int)col[t];
        float2 w = *(const float2*)(dinv2 + 2 * c);
        uint2 g1 = *(const uint2*)(G12 + (size_t)c * 512 + f0);
        uint2 g2 = *(const uint2*)(G12 + (size_t)c * 512 + 256 + f0);
        r0 += w.x * __uint_as_float(g1.x << 16);
        r1 += w.x * __uint_as_float(g1.x & 0xffff0000u);
        r2 += w.x * __uint_as_float(g1.y << 16);
        r3 += w.x * __uint_as_float(g1.y & 0xffff0000u);
        c0 += w.y * __uint_as_float(g2.x << 16);
        c1 += w.y * __uint_as_float(g2.x & 0xffff0000u);
        c2 += w.y * __uint_as_float(g2.y << 16);
        c3 += w.y * __uint_as_float(g2.y & 0xffff0000u);
    }
    float b0, b1, b2, b3;
    int f32io = flags[1];
    if (f32io) {
        const float* bp = (const float*)bias + f0;
        b0 = bp[0]; b1 = bp[1]; b2 = bp[2]; b3 = bp[3];
    } else {
        const unsigned short* bp = (const unsigned short*)bias + f0;
        b0 = bf2f(bp[0]); b1 = bf2f(bp[1]); b2 = bf2f(bp[2]); b3 = bf2f(bp[3]);
    }
    float2 wi = *(const float2*)(dinv2 + 2 * i);
    uint2 gi = *(const uint2*)(G12 + (size_t)i * 512 + f0);
    float z10 = __uint_as_float(gi.x << 16)         - wi.x * r0 + b0;
    float z11 = __uint_as_float(gi.x & 0xffff0000u) - wi.x * r1 + b1;
    float z12 = __uint_as_float(gi.y << 16)         - wi.x * r2 + b2;
    float z13 = __uint_as_float(gi.y & 0xffff0000u) - wi.x * r3 + b3;
    float z20 = wi.y * c0 + b0;
    float z21 = wi.y * c1 + b1;
    float z22 = wi.y * c2 + b2;
    float z23 = wi.y * c3 + b3;
    size_t base = (size_t)i * HH + f0;
    size_t chunk = (size_t)NN * HH;
    if (f32io) {
        float* o = (float*)Oout;
        o[base] = z20; o[base + 1] = z21; o[base + 2] = z22; o[base + 3] = z23;
        o[chunk + base] = z10; o[chunk + base + 1] = z11;
        o[chunk + base + 2] = z12; o[chunk + base + 3] = z13;
        o[2 * chunk + base] = z20; o[2 * chunk + base + 1] = z21;
        o[2 * chunk + base + 2] = z22; o[2 * chunk + base + 3] = z23;
    } else {
        unsigned short* o = (unsigned short*)Oout;
        uint2 p1, p2;
        p1.x = (unsigned int)f2bf(z10) | ((unsigned int)f2bf(z11) << 16);
        p1.y = (unsigned int)f2bf(z12) | ((unsigned int)f2bf(z13) << 16);
        p2.x = (unsigned int)f2bf(z20) | ((unsigned int)f2bf(z21) << 16);
        p2.y = (unsigned int)f2bf(z22) | ((unsigned int)f2bf(z23) << 16);
        *(uint2*)(o + base) = p2;
        *(uint2*)(o + chunk + base) = p1;
        *(uint2*)(o + 2 * chunk + base) = p2;
    }
}

extern "C" void kernel_launch(void* const* d_in, const int* in_sizes, int n_in,
                              void* d_out, int out_size, void* d_ws, size_t ws_size,
                              hipStream_t stream) {
    const void* x = 0; const void* ei = 0;
    const void* W1 = 0; const void* b1 = 0; const void* W2 = 0; const void* b2 = 0;
    for (int i = 0; i < n_in; i++) {
        int s = in_sizes[i];
        if (s == NN * HH) x = d_in[i];
        else if (s == 2 * EE) ei = d_in[i];
        else if (s == HH * HH) { if (!W1) W1 = d_in[i]; else W2 = d_in[i]; }
        else if (s == HH) { if (!b1) b1 = d_in[i]; else b2 = d_in[i]; }
    }

    char* ws = (char*)d_ws;
    size_t off = 0;
    int* flags = (int*)(ws + off); off += 256;
    int* rawcnt = (int*)(ws + off); off += (size_t)NN * 4;
    int* fillc = (int*)(ws + off); off += (size_t)NN * 4;
    int* deg_c = (int*)(ws + off); off += (size_t)NN * 4;
    int* deg_r = (int*)(ws + off); off += (size_t)NN * 4;       // = unique count per row
    int* row_start = (int*)(ws + off); off += (size_t)(NN + 4) * 4;
    float* dinv2 = (float*)(ws + off); off += (size_t)NN * 8;
    unsigned short* col = (unsigned short*)(ws + off); off += (size_t)EE * 2;
    float* W1f = (float*)(ws + off); off += (size_t)HH * HH * 4;
    float* W2f = (float*)(ws + off); off += (size_t)HH * HH * 4;
    unsigned short* G12 = (unsigned short*)(ws + off); off += (size_t)NN * 512 * 2;
    unsigned short* Y = G12;                                     // aliases G12 (dead before G12 written)
    unsigned short* H1 = (unsigned short*)(ws + off); off += (size_t)NN * HH * 2;
    unsigned short* H2 = (unsigned short*)(ws + off); off += (size_t)NN * HH * 2;
    // total ~21.9 MB (proven fits)

    // ---- graph build
    k_detect<<<1, 64, 0, stream>>>((const unsigned int*)x, (const unsigned int*)ei, flags);
    k_zero3<<<(NN + 255) / 256, 256, 0, stream>>>(rawcnt, fillc, deg_c);
    k_wcvt<<<HH * HH / 256, 256, 0, stream>>>(W1, W1f, flags);
    k_wcvt<<<HH * HH / 256, 256, 0, stream>>>(W2, W2f, flags);
    k_count<<<EE / 256, 256, 0, stream>>>(ei, flags, rawcnt);
    k_scan<<<1, 256, 0, stream>>>(rawcnt, row_start);
    k_fill<<<EE / 256, 256, 0, stream>>>(ei, flags, row_start, fillc, col);
    k_dedup<<<NN, 64, 0, stream>>>(row_start, col, deg_r, deg_c);
    k_dinv2<<<(NN + 255) / 256, 256, 0, stream>>>(deg_r, deg_c, dinv2);

    // ---- Y = x @ W1 (shared by both branches)
    k_gemm16<<<625, 256, 0, stream>>>(x, W1f, Y, flags);
    // ---- fused mid layer: h1 (lsym) and h2 (anorm) from one gather of Y
    k_spmm_mid<<<NN / 4, 256, 0, stream>>>(Y, row_start, col, deg_r, dinv2, b1, flags, H1, H2);
    // ---- G1 = h1 @ W2 and G2 = h2 @ W2 in ONE launch (1250 blocks)
    k_gemmG<<<1250, 256, 0, stream>>>(H1, H2, W2f, G12);
    // ---- fused final layer + all three output chunks
    k_spmm_fin<<<NN / 4, 256, 0, stream>>>(G12, row_start, col, deg_r, dinv2, b2, flags, d_out);
}

// Round 6
// 270.451 us; speedup vs baseline: 1.8940x; 1.1986x over previous
//
#include <hip/hip_runtime.h>

#define NN 10000
#define EE 320000
#define HH 256

typedef __attribute__((ext_vector_type(8))) short bf16x8;
typedef __attribute__((ext_vector_type(4))) float f32x4;

__device__ float bf2f(unsigned int v) {
    return __uint_as_float(v << 16);
}
__device__ unsigned short f2bf(float f) {
    unsigned int i = __float_as_uint(f);
    return (unsigned short)((i + 0x7fffu + ((i >> 16) & 1u)) >> 16);
}

// ---- 0. Detect input dtypes (parallel). flags[0]: edge_index int64. flags[1]: floats f32.
__global__ void k_detect(const unsigned int* xu, const unsigned int* eu, int* flags) {
    __shared__ int odd_nz;
    __shared__ int plaus;
    int t = threadIdx.x;
    if (t == 0) { odd_nz = 0; plaus = 0; }
    __syncthreads();
    for (int k = t; k < 256; k += 64) {
        if (eu[2 * k + 1] != 0) atomicOr(&odd_nz, 1);
    }
    unsigned int lo = xu[t] & 0xffffu;
    unsigned int ex = (lo >> 7) & 0xffu;
    if (lo == 0u || (ex >= 90u && ex <= 150u)) atomicAdd(&plaus, 1);
    __syncthreads();
    if (t == 0) {
        flags[0] = odd_nz ? 0 : 1;
        flags[1] = (plaus >= 56) ? 0 : 1;
    }
}

__device__ int eload(const void* ei, int is64, int idx) {
    if (is64) return (int)(((const long long*)ei)[idx]);
    return ((const int*)ei)[idx];
}

// ---- 1. zero atomically-built arrays (ws is poisoned 0xAA each call)
__global__ void k_zero3(int* a, int* b, int* c) {
    int i = blockIdx.x * 256 + threadIdx.x;
    if (i < NN) { a[i] = 0; b[i] = 0; c[i] = 0; }
}

// ---- 2. Swizzle BOTH weight matrices into MFMA B-fragment order (bf16).
//  Bsw[((ks*16 + n)*64 + lane)*8 + j] = B[ks*32 + (lane>>4)*8 + j][n*16 + (lane&15)]
//  Blocks [0,32) handle W1 -> W1sw, [32,64) handle W2 -> W2sw.
__global__ void k_swz(const void* W1, const void* W2, const int* flags,
                      unsigned short* W1sw, unsigned short* W2sw) {
    int b = blockIdx.x;
    const void* W = (b < 32) ? W1 : W2;
    unsigned short* O = (b < 32) ? W1sw : W2sw;
    int g = ((b < 32) ? b : b - 32) * 256 + threadIdx.x;   // 8192 groups of 8
    int lane = g & 63;
    int n = (g >> 6) & 15;
    int ks = g >> 10;                                      // 0..7
    int col = n * 16 + (lane & 15);
    int krow = ks * 32 + ((lane >> 4) & 3) * 8;
    unsigned short v[8];
    if (flags[1]) {
        const float* Wf = (const float*)W;
        #pragma unroll
        for (int j = 0; j < 8; j++) v[j] = f2bf(Wf[(size_t)(krow + j) * HH + col]);
    } else {
        const unsigned short* Wh = (const unsigned short*)W;
        #pragma unroll
        for (int j = 0; j < 8; j++) v[j] = Wh[(size_t)(krow + j) * HH + col];
    }
    uint4 p;
    p.x = (unsigned int)v[0] | ((unsigned int)v[1] << 16);
    p.y = (unsigned int)v[2] | ((unsigned int)v[3] << 16);
    p.z = (unsigned int)v[4] | ((unsigned int)v[5] << 16);
    p.w = (unsigned int)v[6] | ((unsigned int)v[7] << 16);
    *(uint4*)(O + (size_t)g * 8) = p;
}

// ---- 3. raw per-row edge counts (duplicates included)
__global__ void k_count(const void* ei, const int* flags, int* rawcnt) {
    int e = blockIdx.x * 256 + threadIdx.x;
    if (e >= EE) return;
    int is64 = flags[0];
    int r = eload(ei, is64, e);
    int c = eload(ei, is64, EE + e);
    if (r < 0 || r >= NN || c < 0 || c >= NN) return;
    atomicAdd(&rawcnt[r], 1);
}

// ---- 4. exclusive prefix sum over rawcnt -> row_start[0..NN], single block
__global__ void k_scan(const int* cnt, int* row_start) {
    __shared__ int part[256];
    int t = threadIdx.x;
    int base = t * 40;                               // 256*40 = 10240 >= NN+1
    int s = 0;
    for (int k = 0; k < 40; k++) { int i = base + k; if (i < NN) s += cnt[i]; }
    part[t] = s;
    __syncthreads();
    for (int off = 1; off < 256; off <<= 1) {
        int add = (t >= off) ? part[t - off] : 0;
        __syncthreads();
        part[t] += add;
        __syncthreads();
    }
    int run = part[t] - s;
    for (int k = 0; k < 40; k++) {
        int i = base + k;
        if (i <= NN) row_start[i] = run;
        if (i < NN) run += cnt[i];
    }
}

// ---- 5. scatter columns into raw CSR slots (16-bit cols, NN < 65536)
__global__ void k_fill(const void* ei, const int* flags, const int* row_start,
                       int* fillc, unsigned short* col) {
    int e = blockIdx.x * 256 + threadIdx.x;
    if (e >= EE) return;
    int is64 = flags[0];
    int r = eload(ei, is64, e);
    int c = eload(ei, is64, EE + e);
    if (r < 0 || r >= NN || c < 0 || c >= NN) return;
    int pos = row_start[r] + atomicAdd(&fillc[r], 1);
    col[pos] = (unsigned short)c;
}

// ---- 6. per-row dedupe (one wave per row): compact unique cols, count degrees
__global__ void k_dedup(const int* row_start, unsigned short* col,
                        int* deg_r, int* deg_c) {
    __shared__ int lds[192];
    __shared__ int cnt;
    int i = blockIdx.x;
    int lane = threadIdx.x;
    int s = row_start[i];
    int d = row_start[i + 1] - s;
    if (d > 192) d = 192;                            // raw deg ~ Poisson(32); never hit
    if (lane == 0) cnt = 0;
    for (int t = lane; t < d; t += 64) lds[t] = (int)col[s + t];
    __syncthreads();
    for (int t = lane; t < d; t += 64) {
        int c = lds[t];
        int dup = 0;
        for (int u = 0; u < t; u++) { if (lds[u] == c) dup = 1; }
        if (!dup) {
            int p = atomicAdd(&cnt, 1);
            col[s + p] = (unsigned short)c;          // compacted unique prefix
            atomicAdd(&deg_c[c], 1);
        }
    }
    __syncthreads();
    if (lane == 0) deg_r[i] = cnt;
}

// ---- 7. dinv2[i] = (rsqrt(deg_r) | 0, rsqrt(deg_c) | 0) packed float2
__global__ void k_dinv2(const int* deg_r, const int* deg_c, float* dinv2) {
    int i = blockIdx.x * 256 + threadIdx.x;
    if (i >= NN) return;
    int dr = deg_r[i], dc = deg_c[i];
    dinv2[2 * i]     = dr > 0 ? rsqrtf((float)dr) : 0.0f;
    dinv2[2 * i + 1] = dc > 0 ? rsqrtf((float)dc) : 0.0f;
}

// ---- 8. MFMA GEMM: Y = x @ W1. Block = 16 rows x 256 cols, 4 waves.
//  Wave w covers col-tiles [4w, 4w+4). Grid = 625 (16*625 = 10000 exact).
//  A-frag: A[m=lane&15][k=quad*8+j]; B-frag from swizzled Bsw; C/D: col=lane&15, row=quad*4+reg.
__global__ void k_gy(const void* A, const unsigned short* Bsw, unsigned short* C,
                     const int* flags) {
    int wv = threadIdx.x >> 6;
    int lane = threadIdx.x & 63;
    int quad = lane >> 4;
    int l16 = lane & 15;
    int r0 = blockIdx.x * 16;
    int arow = r0 + l16;
    f32x4 acc[4] = {{0,0,0,0},{0,0,0,0},{0,0,0,0},{0,0,0,0}};
    int af32 = flags[1];
    for (int ks = 0; ks < 8; ks++) {
        bf16x8 af;
        if (af32) {
            const float* ap = (const float*)A + (size_t)arow * HH + ks * 32 + quad * 8;
            float4 v0 = *(const float4*)ap;
            float4 v1 = *(const float4*)(ap + 4);
            af[0] = (short)f2bf(v0.x); af[1] = (short)f2bf(v0.y);
            af[2] = (short)f2bf(v0.z); af[3] = (short)f2bf(v0.w);
            af[4] = (short)f2bf(v1.x); af[5] = (short)f2bf(v1.y);
            af[6] = (short)f2bf(v1.z); af[7] = (short)f2bf(v1.w);
        } else {
            af = *(const bf16x8*)((const unsigned short*)A + (size_t)arow * HH + ks * 32 + quad * 8);
        }
        #pragma unroll
        for (int t = 0; t < 4; t++) {
            int n = wv * 4 + t;
            bf16x8 bf = *(const bf16x8*)(Bsw + ((size_t)(ks * 16 + n) * 64 + lane) * 8);
            acc[t] = __builtin_amdgcn_mfma_f32_16x16x32_bf16(af, bf, acc[t], 0, 0, 0);
        }
    }
    #pragma unroll
    for (int t = 0; t < 4; t++) {
        int cn = (wv * 4 + t) * 16 + l16;
        #pragma unroll
        for (int r = 0; r < 4; r++) {
            int row = r0 + quad * 4 + r;
            C[(size_t)row * HH + cn] = f2bf(acc[t][r]);
        }
    }
}

// ---- 9. MFMA GEMM merged: blocks [0,625) G1 = H1@W2 -> G12[:,0:256];
//          [625,1250) G2 = H2@W2 -> G12[:,256:512]. A is bf16.
__global__ void k_gg(const unsigned short* H1, const unsigned short* H2,
                     const unsigned short* Bsw, unsigned short* G12) {
    int wv = threadIdx.x >> 6;
    int lane = threadIdx.x & 63;
    int quad = lane >> 4;
    int l16 = lane & 15;
    int b = blockIdx.x;
    const unsigned short* A = (b < 625) ? H1 : H2;
    int coffs = (b < 625) ? 0 : 256;
    int r0 = ((b < 625) ? b : b - 625) * 16;
    int arow = r0 + l16;
    f32x4 acc[4] = {{0,0,0,0},{0,0,0,0},{0,0,0,0},{0,0,0,0}};
    for (int ks = 0; ks < 8; ks++) {
        bf16x8 af = *(const bf16x8*)(A + (size_t)arow * HH + ks * 32 + quad * 8);
        #pragma unroll
        for (int t = 0; t < 4; t++) {
            int n = wv * 4 + t;
            bf16x8 bf = *(const bf16x8*)(Bsw + ((size_t)(ks * 16 + n) * 64 + lane) * 8);
            acc[t] = __builtin_amdgcn_mfma_f32_16x16x32_bf16(af, bf, acc[t], 0, 0, 0);
        }
    }
    #pragma unroll
    for (int t = 0; t < 4; t++) {
        int cn = coffs + (wv * 4 + t) * 16 + l16;
        #pragma unroll
        for (int r = 0; r < 4; r++) {
            int row = r0 + quad * 4 + r;
            G12[(size_t)row * 512 + cn] = f2bf(acc[t][r]);
        }
    }
}

// ---- 10. Fused mid layer, edge loop unrolled x4 for memory-level parallelism.
__global__ void k_spmm_mid(const unsigned short* Y, const int* row_start,
                           const unsigned short* col, const int* ucnt,
                           const float* dinv2, const void* bias, const int* flags,
                           unsigned short* H1, unsigned short* H2) {
    int wave = threadIdx.x >> 6;
    int lane = threadIdx.x & 63;
    int i = blockIdx.x * 4 + wave;                   // grid = NN/4 exactly
    int f0 = lane * 4;
    float r0 = 0.f, r1 = 0.f, r2 = 0.f, r3 = 0.f;
    float c0 = 0.f, c1 = 0.f, c2 = 0.f, c3 = 0.f;
    int s = row_start[i];
    int e = s + ucnt[i];
    int e4 = s + ((e - s) & ~3);
    int t = s;
    for (; t < e4; t += 4) {
        int ca = (int)col[t];
        int cb = (int)col[t + 1];
        int cc = (int)col[t + 2];
        int cd = (int)col[t + 3];
        float2 wa = *(const float2*)(dinv2 + 2 * ca);
        float2 wb = *(const float2*)(dinv2 + 2 * cb);
        float2 wc = *(const float2*)(dinv2 + 2 * cc);
        float2 wd = *(const float2*)(dinv2 + 2 * cd);
        uint2 ya = *(const uint2*)(Y + (size_t)ca * HH + f0);
        uint2 yb = *(const uint2*)(Y + (size_t)cb * HH + f0);
        uint2 yc = *(const uint2*)(Y + (size_t)cc * HH + f0);
        uint2 yd = *(const uint2*)(Y + (size_t)cd * HH + f0);
        float y0, y1, y2, y3;
        y0 = __uint_as_float(ya.x << 16); y1 = __uint_as_float(ya.x & 0xffff0000u);
        y2 = __uint_as_float(ya.y << 16); y3 = __uint_as_float(ya.y & 0xffff0000u);
        r0 += wa.x * y0; r1 += wa.x * y1; r2 += wa.x * y2; r3 += wa.x * y3;
        c0 += wa.y * y0; c1 += wa.y * y1; c2 += wa.y * y2; c3 += wa.y * y3;
        y0 = __uint_as_float(yb.x << 16); y1 = __uint_as_float(yb.x & 0xffff0000u);
        y2 = __uint_as_float(yb.y << 16); y3 = __uint_as_float(yb.y & 0xffff0000u);
        r0 += wb.x * y0; r1 += wb.x * y1; r2 += wb.x * y2; r3 += wb.x * y3;
        c0 += wb.y * y0; c1 += wb.y * y1; c2 += wb.y * y2; c3 += wb.y * y3;
        y0 = __uint_as_float(yc.x << 16); y1 = __uint_as_float(yc.x & 0xffff0000u);
        y2 = __uint_as_float(yc.y << 16); y3 = __uint_as_float(yc.y & 0xffff0000u);
        r0 += wc.x * y0; r1 += wc.x * y1; r2 += wc.x * y2; r3 += wc.x * y3;
        c0 += wc.y * y0; c1 += wc.y * y1; c2 += wc.y * y2; c3 += wc.y * y3;
        y0 = __uint_as_float(yd.x << 16); y1 = __uint_as_float(yd.x & 0xffff0000u);
        y2 = __uint_as_float(yd.y << 16); y3 = __uint_as_float(yd.y & 0xffff0000u);
        r0 += wd.x * y0; r1 += wd.x * y1; r2 += wd.x * y2; r3 += wd.x * y3;
        c0 += wd.y * y0; c1 += wd.y * y1; c2 += wd.y * y2; c3 += wd.y * y3;
    }
    for (; t < e; t++) {
        int c = (int)col[t];
        float2 w = *(const float2*)(dinv2 + 2 * c);
        uint2 raw = *(const uint2*)(Y + (size_t)c * HH + f0);
        float y0 = __uint_as_float(raw.x << 16);
        float y1 = __uint_as_float(raw.x & 0xffff0000u);
        float y2 = __uint_as_float(raw.y << 16);
        float y3 = __uint_as_float(raw.y & 0xffff0000u);
        r0 += w.x * y0; r1 += w.x * y1; r2 += w.x * y2; r3 += w.x * y3;
        c0 += w.y * y0; c1 += w.y * y1; c2 += w.y * y2; c3 += w.y * y3;
    }
    float b0, b1, b2, b3;
    if (flags[1]) {
        const float* bp = (const float*)bias + f0;
        b0 = bp[0]; b1 = bp[1]; b2 = bp[2]; b3 = bp[3];
    } else {
        const unsigned short* bp = (const unsigned short*)bias + f0;
        b0 = bf2f(bp[0]); b1 = bf2f(bp[1]); b2 = bf2f(bp[2]); b3 = bf2f(bp[3]);
    }
    float2 wi = *(const float2*)(dinv2 + 2 * i);
    uint2 yr = *(const uint2*)(Y + (size_t)i * HH + f0);
    float yi0 = __uint_as_float(yr.x << 16);
    float yi1 = __uint_as_float(yr.x & 0xffff0000u);
    float yi2 = __uint_as_float(yr.y << 16);
    float yi3 = __uint_as_float(yr.y & 0xffff0000u);
    float h10 = fmaxf(0.f, yi0 - wi.x * r0 + b0);
    float h11 = fmaxf(0.f, yi1 - wi.x * r1 + b1);
    float h12 = fmaxf(0.f, yi2 - wi.x * r2 + b2);
    float h13 = fmaxf(0.f, yi3 - wi.x * r3 + b3);
    float h20 = fmaxf(0.f, wi.y * c0 + b0);
    float h21 = fmaxf(0.f, wi.y * c1 + b1);
    float h22 = fmaxf(0.f, wi.y * c2 + b2);
    float h23 = fmaxf(0.f, wi.y * c3 + b3);
    uint2 p1, p2;
    p1.x = (unsigned int)f2bf(h10) | ((unsigned int)f2bf(h11) << 16);
    p1.y = (unsigned int)f2bf(h12) | ((unsigned int)f2bf(h13) << 16);
    p2.x = (unsigned int)f2bf(h20) | ((unsigned int)f2bf(h21) << 16);
    p2.y = (unsigned int)f2bf(h22) | ((unsigned int)f2bf(h23) << 16);
    *(uint2*)(H1 + (size_t)i * HH + f0) = p1;
    *(uint2*)(H2 + (size_t)i * HH + f0) = p2;
}

// ---- 11. Fused final layer, edge loop unrolled x4.
__global__ void k_spmm_fin(const unsigned short* G12, const int* row_start,
                           const unsigned short* col, const int* ucnt,
                           const float* dinv2, const void* bias, const int* flags,
                           void* Oout) {
    int wave = threadIdx.x >> 6;
    int lane = threadIdx.x & 63;
    int i = blockIdx.x * 4 + wave;
    int f0 = lane * 4;
    float r0 = 0.f, r1 = 0.f, r2 = 0.f, r3 = 0.f;
    float c0 = 0.f, c1 = 0.f, c2 = 0.f, c3 = 0.f;
    int s = row_start[i];
    int e = s + ucnt[i];
    int e4 = s + ((e - s) & ~3);
    int t = s;
    for (; t < e4; t += 4) {
        int ca = (int)col[t];
        int cb = (int)col[t + 1];
        int cc = (int)col[t + 2];
        int cd = (int)col[t + 3];
        float2 wa = *(const float2*)(dinv2 + 2 * ca);
        float2 wb = *(const float2*)(dinv2 + 2 * cb);
        float2 wc = *(const float2*)(dinv2 + 2 * cc);
        float2 wd = *(const float2*)(dinv2 + 2 * cd);
        uint2 g1a = *(const uint2*)(G12 + (size_t)ca * 512 + f0);
        uint2 g2a = *(const uint2*)(G12 + (size_t)ca * 512 + 256 + f0);
        uint2 g1b = *(const uint2*)(G12 + (size_t)cb * 512 + f0);
        uint2 g2b = *(const uint2*)(G12 + (size_t)cb * 512 + 256 + f0);
        uint2 g1c = *(const uint2*)(G12 + (size_t)cc * 512 + f0);
        uint2 g2c = *(const uint2*)(G12 + (size_t)cc * 512 + 256 + f0);
        uint2 g1d = *(const uint2*)(G12 + (size_t)cd * 512 + f0);
        uint2 g2d = *(const uint2*)(G12 + (size_t)cd * 512 + 256 + f0);
        r0 += wa.x * __uint_as_float(g1a.x << 16);
        r1 += wa.x * __uint_as_float(g1a.x & 0xffff0000u);
        r2 += wa.x * __uint_as_float(g1a.y << 16);
        r3 += wa.x * __uint_as_float(g1a.y & 0xffff0000u);
        c0 += wa.y * __uint_as_float(g2a.x << 16);
        c1 += wa.y * __uint_as_float(g2a.x & 0xffff0000u);
        c2 += wa.y * __uint_as_float(g2a.y << 16);
        c3 += wa.y * __uint_as_float(g2a.y & 0xffff0000u);
        r0 += wb.x * __uint_as_float(g1b.x << 16);
        r1 += wb.x * __uint_as_float(g1b.x & 0xffff0000u);
        r2 += wb.x * __uint_as_float(g1b.y << 16);
        r3 += wb.x * __uint_as_float(g1b.y & 0xffff0000u);
        c0 += wb.y * __uint_as_float(g2b.x << 16);
        c1 += wb.y * __uint_as_float(g2b.x & 0xffff0000u);
        c2 += wb.y * __uint_as_float(g2b.y << 16);
        c3 += wb.y * __uint_as_float(g2b.y & 0xffff0000u);
        r0 += wc.x * __uint_as_float(g1c.x << 16);
        r1 += wc.x * __uint_as_float(g1c.x & 0xffff0000u);
        r2 += wc.x * __uint_as_float(g1c.y << 16);
        r3 += wc.x * __uint_as_float(g1c.y & 0xffff0000u);
        c0 += wc.y * __uint_as_float(g2c.x << 16);
        c1 += wc.y * __uint_as_float(g2c.x & 0xffff0000u);
        c2 += wc.y * __uint_as_float(g2c.y << 16);
        c3 += wc.y * __uint_as_float(g2c.y & 0xffff0000u);
        r0 += wd.x * __uint_as_float(g1d.x << 16);
        r1 += wd.x * __uint_as_float(g1d.x & 0xffff0000u);
        r2 += wd.x * __uint_as_float(g1d.y << 16);
        r3 += wd.x * __uint_as_float(g1d.y & 0xffff0000u);
        c0 += wd.y * __uint_as_float(g2d.x << 16);
        c1 += wd.y * __uint_as_float(g2d.x & 0xffff0000u);
        c2 += wd.y * __uint_as_float(g2d.y << 16);
        c3 += wd.y * __uint_as_float(g2d.y & 0xffff0000u);
    }
    for (; t < e; t++) {
        int c = (int)col[t];
        float2 w = *(const float2*)(dinv2 + 2 * c);
        uint2 g1 = *(const uint2*)(G12 + (size_t)c * 512 + f0);
        uint2 g2 = *(const uint2*)(G12 + (size_t)c * 512 + 256 + f0);
        r0 += w.x * __uint_as_float(g1.x << 16);
        r1 += w.x * __uint_as_float(g1.x & 0xffff0000u);
        r2 += w.x * __uint_as_float(g1.y << 16);
        r3 += w.x * __uint_as_float(g1.y & 0xffff0000u);
        c0 += w.y * __uint_as_float(g2.x << 16);
        c1 += w.y * __uint_as_float(g2.x & 0xffff0000u);
        c2 += w.y * __uint_as_float(g2.y << 16);
        c3 += w.y * __uint_as_float(g2.y & 0xffff0000u);
    }
    float b0, b1, b2, b3;
    int f32io = flags[1];
    if (f32io) {
        const float* bp = (const float*)bias + f0;
        b0 = bp[0]; b1 = bp[1]; b2 = bp[2]; b3 = bp[3];
    } else {
        const unsigned short* bp = (const unsigned short*)bias + f0;
        b0 = bf2f(bp[0]); b1 = bf2f(bp[1]); b2 = bf2f(bp[2]); b3 = bf2f(bp[3]);
    }
    float2 wi = *(const float2*)(dinv2 + 2 * i);
    uint2 gi = *(const uint2*)(G12 + (size_t)i * 512 + f0);
    float z10 = __uint_as_float(gi.x << 16)         - wi.x * r0 + b0;
    float z11 = __uint_as_float(gi.x & 0xffff0000u) - wi.x * r1 + b1;
    float z12 = __uint_as_float(gi.y << 16)         - wi.x * r2 + b2;
    float z13 = __uint_as_float(gi.y & 0xffff0000u) - wi.x * r3 + b3;
    float z20 = wi.y * c0 + b0;
    float z21 = wi.y * c1 + b1;
    float z22 = wi.y * c2 + b2;
    float z23 = wi.y * c3 + b3;
    size_t base = (size_t)i * HH + f0;
    size_t chunk = (size_t)NN * HH;
    if (f32io) {
        float* o = (float*)Oout;
        o[base] = z20; o[base + 1] = z21; o[base + 2] = z22; o[base + 3] = z23;
        o[chunk + base] = z10; o[chunk + base + 1] = z11;
        o[chunk + base + 2] = z12; o[chunk + base + 3] = z13;
        o[2 * chunk + base] = z20; o[2 * chunk + base + 1] = z21;
        o[2 * chunk + base + 2] = z22; o[2 * chunk + base + 3] = z23;
    } else {
        unsigned short* o = (unsigned short*)Oout;
        uint2 p1, p2;
        p1.x = (unsigned int)f2bf(z10) | ((unsigned int)f2bf(z11) << 16);
        p1.y = (unsigned int)f2bf(z12) | ((unsigned int)f2bf(z13) << 16);
        p2.x = (unsigned int)f2bf(z20) | ((unsigned int)f2bf(z21) << 16);
        p2.y = (unsigned int)f2bf(z22) | ((unsigned int)f2bf(z23) << 16);
        *(uint2*)(o + base) = p2;
        *(uint2*)(o + chunk + base) = p1;
        *(uint2*)(o + 2 * chunk + base) = p2;
    }
}

extern "C" void kernel_launch(void* const* d_in, const int* in_sizes, int n_in,
                              void* d_out, int out_size, void* d_ws, size_t ws_size,
                              hipStream_t stream) {
    const void* x = 0; const void* ei = 0;
    const void* W1 = 0; const void* b1 = 0; const void* W2 = 0; const void* b2 = 0;
    for (int i = 0; i < n_in; i++) {
        int s = in_sizes[i];
        if (s == NN * HH) x = d_in[i];
        else if (s == 2 * EE) ei = d_in[i];
        else if (s == HH * HH) { if (!W1) W1 = d_in[i]; else W2 = d_in[i]; }
        else if (s == HH) { if (!b1) b1 = d_in[i]; else b2 = d_in[i]; }
    }

    char* ws = (char*)d_ws;
    size_t off = 0;
    int* flags = (int*)(ws + off); off += 256;
    int* rawcnt = (int*)(ws + off); off += (size_t)NN * 4;
    int* fillc = (int*)(ws + off); off += (size_t)NN * 4;
    int* deg_c = (int*)(ws + off); off += (size_t)NN * 4;
    int* deg_r = (int*)(ws + off); off += (size_t)NN * 4;       // = unique count per row
    int* row_start = (int*)(ws + off); off += (size_t)(NN + 4) * 4;
    float* dinv2 = (float*)(ws + off); off += (size_t)NN * 8;
    unsigned short* col = (unsigned short*)(ws + off); off += (size_t)EE * 2;
    unsigned short* W1sw = (unsigned short*)(ws + off); off += (size_t)HH * HH * 2;
    unsigned short* W2sw = (unsigned short*)(ws + off); off += (size_t)HH * HH * 2;
    unsigned short* G12 = (unsigned short*)(ws + off); off += (size_t)NN * 512 * 2;
    unsigned short* Y = G12;                                     // aliases G12 (dead before G12 written)
    unsigned short* H1 = (unsigned short*)(ws + off); off += (size_t)NN * HH * 2;
    unsigned short* H2 = (unsigned short*)(ws + off); off += (size_t)NN * HH * 2;
    // total ~21.7 MB (proven fits)

    // ---- graph build
    k_detect<<<1, 64, 0, stream>>>((const unsigned int*)x, (const unsigned int*)ei, flags);
    k_zero3<<<(NN + 255) / 256, 256, 0, stream>>>(rawcnt, fillc, deg_c);
    k_swz<<<64, 256, 0, stream>>>(W1, W2, flags, W1sw, W2sw);
    k_count<<<EE / 256, 256, 0, stream>>>(ei, flags, rawcnt);
    k_scan<<<1, 256, 0, stream>>>(rawcnt, row_start);
    k_fill<<<EE / 256, 256, 0, stream>>>(ei, flags, row_start, fillc, col);
    k_dedup<<<NN, 64, 0, stream>>>(row_start, col, deg_r, deg_c);
    k_dinv2<<<(NN + 255) / 256, 256, 0, stream>>>(deg_r, deg_c, dinv2);

    // ---- Y = x @ W1 (shared by both branches), MFMA
    k_gy<<<625, 256, 0, stream>>>(x, W1sw, Y, flags);
    // ---- fused mid layer: h1 (lsym) and h2 (anorm) from one gather of Y
    k_spmm_mid<<<NN / 4, 256, 0, stream>>>(Y, row_start, col, deg_r, dinv2, b1, flags, H1, H2);
    // ---- G1 = h1 @ W2 and G2 = h2 @ W2 in ONE MFMA launch (1250 blocks)
    k_gg<<<1250, 256, 0, stream>>>(H1, H2, W2sw, G12);
    // ---- fused final layer + all three output chunks
    k_spmm_fin<<<NN / 4, 256, 0, stream>>>(G12, row_start, col, deg_r, dinv2, b2, flags, d_out);
}